// Round 7
// baseline (1089.882 us; speedup 1.0000x reference)
//
#include <hip/hip_runtime.h>
#include <math.h>

#define TT   512
#define BB   64
#define EMBD 512
#define HIDD 512

typedef _Float16 half2v __attribute__((ext_vector_type(2)));

__device__ __forceinline__ float fdot2(unsigned a, unsigned b, float c) {
  half2v av = __builtin_bit_cast(half2v, a);
  half2v bv = __builtin_bit_cast(half2v, b);
#if __has_builtin(__builtin_amdgcn_fdot2)
  return __builtin_amdgcn_fdot2(av, bv, c, false);
#else
  return c + (float)av.x * (float)bv.x + (float)av.y * (float)bv.y;
#endif
}

__device__ __forceinline__ float fast_tanh(float x) {
  float e = __expf(2.0f * x);
  return 1.0f - 2.0f * __builtin_amdgcn_rcpf(e + 1.0f);
}

__device__ __forceinline__ unsigned pack2(float a, float b) {
  half2v hv; hv.x = (_Float16)a; hv.y = (_Float16)b;
  return __builtin_bit_cast(unsigned, hv);
}

// ---------------------------------------------------------------------------
// K0: repack fp32 W1h -> fp16 chunks (identical layout to round 6).
// elman thread tid: w=tid>>6, l=tid&63, qa=l>>4, jg=l&15.
// chunk c (0..63): jo=c&3, kq=c>>2. Covers j=64w+4jg+jo, k=128qa+8kq..+8,
// packed as 4 dwords of (even,odd) fp16 pairs. wp[c*512+tid].
// ---------------------------------------------------------------------------
__global__ __launch_bounds__(256) void repack_w1h(
    const float* __restrict__ W1, uint4* __restrict__ wp)
{
  const int gid = blockIdx.x * 256 + threadIdx.x;   // 0..32767
  const int c   = gid >> 9;
  const int tid = gid & 511;
  const int w = tid >> 6, l = tid & 63;
  const int qa = l >> 4, jg = l & 15;
  const int jo = c & 3, kq = c >> 2;
  const int j  = 64 * w + 4 * jg + jo;
  const int k0 = 128 * qa + 8 * kq;
  const float* src = W1 + (size_t)j * (2 * EMBD) + EMBD + k0;
  unsigned r[4];
#pragma unroll
  for (int q = 0; q < 4; q++) r[q] = pack2(src[2 * q], src[2 * q + 1]);
  uint4 u; u.x = r[0]; u.y = r[1]; u.z = r[2]; u.w = r[3];
  wp[gid] = u;
}

// ---------------------------------------------------------------------------
// K1: px[m][j] = b1[j] + sum_k emb[x[m]][k] * W1[j][k]  (fp32 tile GEMM)
// ---------------------------------------------------------------------------
__global__ __launch_bounds__(256) void px_gemm(
    const int* __restrict__ x, const float* __restrict__ emb,
    const float* __restrict__ W1, const float* __restrict__ b1,
    float* __restrict__ px)
{
  __shared__ float As[8][132];
  __shared__ float Bs[8][132];
  __shared__ int stok[128];
  const int tid = threadIdx.x;
  const int m0 = blockIdx.x * 128;
  const int j0 = blockIdx.y * 128;
  if (tid < 128) stok[tid] = x[m0 + tid];
  __syncthreads();
  const int lr = tid >> 1;
  const int lh = (tid & 1) * 4;
  const int ty = tid >> 4, tx = tid & 15;
  const size_t arow = (size_t)stok[lr] * EMBD;
  const float* brow = W1 + (size_t)(j0 + lr) * (2 * EMBD);

  float acc[8][8];
#pragma unroll
  for (int i = 0; i < 8; i++)
#pragma unroll
    for (int q = 0; q < 8; q++) acc[i][q] = 0.f;

  for (int k0 = 0; k0 < EMBD; k0 += 8) {
    float4 av = *(const float4*)(emb + arow + k0 + lh);
    float4 bv = *(const float4*)(brow + k0 + lh);
    __syncthreads();
    As[lh + 0][lr] = av.x; As[lh + 1][lr] = av.y; As[lh + 2][lr] = av.z; As[lh + 3][lr] = av.w;
    Bs[lh + 0][lr] = bv.x; Bs[lh + 1][lr] = bv.y; Bs[lh + 2][lr] = bv.z; Bs[lh + 3][lr] = bv.w;
    __syncthreads();
#pragma unroll
    for (int kk = 0; kk < 8; kk++) {
      float4 a0 = *(const float4*)&As[kk][ty * 8];
      float4 a1 = *(const float4*)&As[kk][ty * 8 + 4];
      float4 c0 = *(const float4*)&Bs[kk][tx * 8];
      float4 c1 = *(const float4*)&Bs[kk][tx * 8 + 4];
      float a[8] = {a0.x,a0.y,a0.z,a0.w,a1.x,a1.y,a1.z,a1.w};
      float bb[8] = {c0.x,c0.y,c0.z,c0.w,c1.x,c1.y,c1.z,c1.w};
#pragma unroll
      for (int i = 0; i < 8; i++)
#pragma unroll
        for (int q = 0; q < 8; q++)
          acc[i][q] = fmaf(a[i], bb[q], acc[i][q]);
    }
  }
  const float* bp = b1 + j0 + tx * 8;
  float bias0[8];
#pragma unroll
  for (int q = 0; q < 8; q++) bias0[q] = bp[q];
#pragma unroll
  for (int i = 0; i < 8; i++) {
    float o[8];
#pragma unroll
    for (int q = 0; q < 8; q++) o[q] = acc[i][q] + bias0[q];
    float* dst = px + (size_t)(m0 + ty * 8 + i) * HIDD + j0 + tx * 8;
    *(float4*)dst       = make_float4(o[0], o[1], o[2], o[3]);
    *(float4*)(dst + 4) = make_float4(o[4], o[5], o[6], o[7]);
  }
}

// ---------------------------------------------------------------------------
// K2: recurrence v7 — SINGLE code path (no attribute, no template fallback).
// 64 wgs x 512 thr, 1 wg/CU. Weight residency per thread (64 uint4 total):
//   54 chunks in registers (216 dwords; unified VGPR+AGPR file),
//   4 chunks static LDS (32 KB, kq 13), 6 chunks dynamic LDS (48 KB,
//   kq 14 + kq 15 jo0/jo1). kq15 jo2/jo3 live in wr[52..53].
// ZERO per-step global streaming. h chunks at p=kq*4+qa (conflict-free).
// One barrier/step; 2-level shfl_xor merge.
// ---------------------------------------------------------------------------
#define DOT4(HH, W0, W1v, W2v, W3v) do {                                    \
    const uint4 hh = (HH);                                                  \
    a0=fdot2((W0).x,hh.x,a0);  a0=fdot2((W0).y,hh.y,a0);                    \
    a0=fdot2((W0).z,hh.z,a0);  a0=fdot2((W0).w,hh.w,a0);                    \
    a1=fdot2((W1v).x,hh.x,a1); a1=fdot2((W1v).y,hh.y,a1);                   \
    a1=fdot2((W1v).z,hh.z,a1); a1=fdot2((W1v).w,hh.w,a1);                   \
    a2=fdot2((W2v).x,hh.x,a2); a2=fdot2((W2v).y,hh.y,a2);                   \
    a2=fdot2((W2v).z,hh.z,a2); a2=fdot2((W2v).w,hh.w,a2);                   \
    a3=fdot2((W3v).x,hh.x,a3); a3=fdot2((W3v).y,hh.y,a3);                   \
    a3=fdot2((W3v).z,hh.z,a3); a3=fdot2((W3v).w,hh.w,a3);                   \
  } while (0)

__attribute__((amdgpu_flat_work_group_size(512, 512), amdgpu_waves_per_eu(2)))
__global__ void elman_v7(
    const uint4* __restrict__ wp, const float* __restrict__ px,
    const float* __restrict__ W2, const float* __restrict__ b2,
    float* __restrict__ out)
{
  extern __shared__ uint4 wdyn[];      // 6*512 uint4 = 48 KB (c 56..61)
  __shared__ uint4 wstat[4 * 512];     // 32 KB (c 52..55, = kq 13)
  __shared__ uint4 h2[2][64];          // packed fp16 h, dbuf, p = kq*4+qa
  __shared__ float red[2][8];

  const int b   = blockIdx.x;
  const int tid = threadIdx.x;
  const int w   = tid >> 6, l = tid & 63;
  const int qa  = l >> 4, jg = l & 15;

  // prologue: 54 reg chunks + 10 LDS chunks (all coalesced)
  uint4 wr[54];
#pragma unroll
  for (int i = 0; i < 52; i++) wr[i] = wp[(size_t)i * 512 + tid];
  wr[52] = wp[(size_t)62 * 512 + tid];          // kq15 jo2
  wr[53] = wp[(size_t)63 * 512 + tid];          // kq15 jo3
#pragma unroll
  for (int i = 0; i < 4; i++) wstat[i * 512 + tid] = wp[(size_t)(52 + i) * 512 + tid];
#pragma unroll
  for (int i = 0; i < 6; i++) wdyn[i * 512 + tid] = wp[(size_t)(56 + i) * 512 + tid];
  if (tid < 64) {
    uint4 z; z.x = z.y = z.z = z.w = 0u;
    h2[0][tid] = z;
  }
  __syncthreads();

  const float* pxb = px + (size_t)b * TT * HIDD;
  float rm0 = -INFINITY, rm1 = -INFINITY, rm2 = -INFINITY, rm3 = -INFINITY;

  for (int t = 0; t < TT; t++) {
    const int cur = t & 1;

    // early issue: px for finalize lanes (latency hidden under the dot)
    float4 pxv = make_float4(0.f, 0.f, 0.f, 0.f);
    if (l < 16)
      pxv = *(const float4*)(pxb + (size_t)t * HIDD + 64 * w + 4 * jg);

    const uint4* hb = &h2[cur][0];
    float a0 = 0.f, a1 = 0.f, a2 = 0.f, a3 = 0.f;

    // kq 0..12: register weights
#pragma unroll
    for (int kq = 0; kq < 13; kq++)
      DOT4(hb[kq * 4 + qa], wr[4 * kq + 0], wr[4 * kq + 1], wr[4 * kq + 2], wr[4 * kq + 3]);
    // kq 13: static LDS
    DOT4(hb[13 * 4 + qa], wstat[0 * 512 + tid], wstat[1 * 512 + tid],
         wstat[2 * 512 + tid], wstat[3 * 512 + tid]);
    // kq 14: dynamic LDS
    DOT4(hb[14 * 4 + qa], wdyn[0 * 512 + tid], wdyn[1 * 512 + tid],
         wdyn[2 * 512 + tid], wdyn[3 * 512 + tid]);
    // kq 15: dynamic LDS (jo0,jo1) + registers (jo2,jo3)
    DOT4(hb[15 * 4 + qa], wdyn[4 * 512 + tid], wdyn[5 * 512 + tid],
         wr[52], wr[53]);

    // merge across 4 k-quarters
    a0 += __shfl_xor(a0, 16); a1 += __shfl_xor(a1, 16);
    a2 += __shfl_xor(a2, 16); a3 += __shfl_xor(a3, 16);
    a0 += __shfl_xor(a0, 32); a1 += __shfl_xor(a1, 32);
    a2 += __shfl_xor(a2, 32); a3 += __shfl_xor(a3, 32);

    if (l < 16) {
      float h0 = fast_tanh(a0 + pxv.x);
      float h1 = fast_tanh(a1 + pxv.y);
      float h2n = fast_tanh(a2 + pxv.z);
      float h3 = fast_tanh(a3 + pxv.w);
      rm0 = fmaxf(rm0, h0); rm1 = fmaxf(rm1, h1);
      rm2 = fmaxf(rm2, h2n); rm3 = fmaxf(rm3, h3);
      // write h[j0..j0+3], j0 = 64w+4jg, into p = kqw*4+qw layout
      const int qw  = w >> 1;
      const int kqw = (w & 1) * 8 + (jg >> 1);
      const int di  = (kqw * 4 + qw) * 4 + (jg & 1) * 2;   // dword index
      unsigned* hw = (unsigned*)&h2[cur ^ 1][0];
      *(uint2*)&hw[di] = make_uint2(pack2(h0, h1), pack2(h2n, h3));
      if (t == TT - 1)
        *(float4*)(out + 2 * BB + (size_t)b * HIDD + 64 * w + 4 * jg) =
            make_float4(h0, h1, h2n, h3);
    }
    __syncthreads();
  }

  // pooled max -> logits (pl overlays dynamic weight LDS; weights dead now)
  float* pl = (float*)wdyn;
  if (l < 16)
    *(float4*)&pl[64 * w + 4 * jg] = make_float4(rm0, rm1, rm2, rm3);
  __syncthreads();
  {
    float pv = pl[tid];
    float q0 = pv * W2[tid];
    float q1 = pv * W2[HIDD + tid];
#pragma unroll
    for (int off = 32; off; off >>= 1) {
      q0 += __shfl_down(q0, off);
      q1 += __shfl_down(q1, off);
    }
    const int wv = tid >> 6, ln = tid & 63;
    if (ln == 0) { red[0][wv] = q0; red[1][wv] = q1; }
  }
  __syncthreads();
  if (tid < 2) {
    float s = b2[tid];
#pragma unroll
    for (int i = 0; i < 8; i++) s += red[tid][i];
    out[b * 2 + tid] = s;
  }
}

// ---------------------------------------------------------------------------
extern "C" void kernel_launch(void* const* d_in, const int* in_sizes, int n_in,
                              void* d_out, int out_size, void* d_ws, size_t ws_size,
                              hipStream_t stream)
{
  const int*   x   = (const int*)d_in[0];
  const float* emb = (const float*)d_in[1];
  const float* W1  = (const float*)d_in[2];
  const float* b1  = (const float*)d_in[3];
  const float* W2  = (const float*)d_in[4];
  const float* b2  = (const float*)d_in[5];
  float* out = (float*)d_out;
  char* ws = (char*)d_ws;

  uint4* wp = (uint4*)ws;                        // 512 KB repacked fp16 W1h
  float* px = (float*)(ws + (1 << 19));          // 64 MB
  const size_t need = (size_t)(1 << 19) + (size_t)BB * TT * HIDD * sizeof(float);
  if (ws_size < need) return;

  repack_w1h<<<128, 256, 0, stream>>>(W1, wp);
  {
    dim3 g(TT * BB / 128, HIDD / 128);           // (256, 4)
    px_gemm<<<g, 256, 0, stream>>>(x, emb, W1, b1, px);
  }

  const size_t dynBytes = (size_t)6 * 512 * sizeof(uint4);   // 48 KB (proven launchable)
  elman_v7<<<dim3(BB), dim3(512), dynBytes, stream>>>(wp, px, W2, b2, out);
}